// Round 2
// baseline (8930.938 us; speedup 1.0000x reference)
//
#include <hip/hip_runtime.h>
#include <math.h>

#define B_DIM   8192
#define N_DIM   784
#define NPAD    800          // 25*32, K/N pad for NN GEMM / Rbf
#define NROWS_W 1024         // 4*256, row-pad for Wbf (NT B operand, 256-wide n-tiles)
#define M_DIM   2048
#define XSZ     (B_DIM*N_DIM)
#define GSZ     (B_DIM*M_DIM)
#define NITER   50
#define PITER   100

typedef __attribute__((ext_vector_type(8))) short short8;
typedef __attribute__((ext_vector_type(4))) float floatx4;

// ---------------- async global->LDS (16B per lane, wave-uniform LDS base) ----------------
__device__ __forceinline__ void async_ld16(const unsigned short* g, unsigned short* l){
  __builtin_amdgcn_global_load_lds(
      (const __attribute__((address_space(1))) unsigned int*)g,
      (__attribute__((address_space(3))) unsigned int*)l,
      16, 0, 0);
}

// ---------------- threefry + erfinv (reproduce jax.random.normal(key(1),(1,2048))) ------------
__device__ __forceinline__ unsigned rotl32(unsigned x, int d){ return (x<<d)|(x>>(32-d)); }

__device__ void threefry2x32(unsigned& v0, unsigned& v1){
  const unsigned ks0=0u, ks1=1u, ks2=0x1BD11BDBu;
  unsigned x0=v0+ks0, x1=v1+ks1;
#define RND(R) { x0+=x1; x1=rotl32(x1,R); x1^=x0; }
  RND(13) RND(15) RND(26) RND(6)
  x0+=ks1; x1+=ks2+1u;
  RND(17) RND(29) RND(16) RND(24)
  x0+=ks2; x1+=ks0+2u;
  RND(13) RND(15) RND(26) RND(6)
  x0+=ks0; x1+=ks1+3u;
  RND(17) RND(29) RND(16) RND(24)
  x0+=ks1; x1+=ks2+4u;
  RND(13) RND(15) RND(26) RND(6)
  x0+=ks2; x1+=ks0+5u;
#undef RND
  v0=x0; v1=x1;
}

__device__ float erfinv_f(float x){
  float w = -logf((1.0f-x)*(1.0f+x));
  float p;
  if (w < 5.0f){
    w -= 2.5f;
    p = 2.81022636e-08f;
    p = fmaf(p,w, 3.43273939e-07f);
    p = fmaf(p,w,-3.5233877e-06f);
    p = fmaf(p,w,-4.39150654e-06f);
    p = fmaf(p,w, 0.00021858087f);
    p = fmaf(p,w,-0.00125372503f);
    p = fmaf(p,w,-0.00417768164f);
    p = fmaf(p,w, 0.246640727f);
    p = fmaf(p,w, 1.50140941f);
  } else {
    w = sqrtf(w) - 3.0f;
    p = -0.000200214257f;
    p = fmaf(p,w, 0.000100950558f);
    p = fmaf(p,w, 0.00134934322f);
    p = fmaf(p,w,-0.00367342844f);
    p = fmaf(p,w, 0.00573950773f);
    p = fmaf(p,w,-0.0076224613f);
    p = fmaf(p,w, 0.00943887047f);
    p = fmaf(p,w, 1.00167406f);
    p = fmaf(p,w, 2.83297682f);
  }
  return p*x;
}

__device__ float bits_to_normal(unsigned b){
  unsigned fb = (b>>9) | 0x3f800000u;
  float u01 = __uint_as_float(fb) - 1.0f;
  const float lo = -0.99999994f;
  float u = u01*(1.0f - lo) + lo;
  u = fmaxf(lo, u);
  return 1.41421356237f * erfinv_f(u);
}

__global__ void setup_kernel(float* __restrict__ xbuf0, float* __restrict__ accs,
                             float* __restrict__ dbuf){
  int i = threadIdx.x;   // 1024 threads
  if (i < 64) accs[i] = 0.0f;
  if (i < 128) dbuf[i] = (i==0) ? 1.0f : 0.0f;
  unsigned v0 = (unsigned)i, v1 = (unsigned)(1024+i);
  threefry2x32(v0, v1);
  xbuf0[i]        = bits_to_normal(v0);
  xbuf0[1024 + i] = bits_to_normal(v1);
}

// ---------------- bf16 convert helpers ----------------
__device__ __forceinline__ unsigned short f2bf(float f){
  unsigned u = __float_as_uint(f);
  unsigned r = (u + 0x7fffu + ((u>>16)&1u)) >> 16;
  return (unsigned short)r;
}
__device__ __forceinline__ unsigned pack2(float a, float b){
  return (unsigned)f2bf(a) | ((unsigned)f2bf(b) << 16);
}
__device__ __forceinline__ float bf2f(unsigned short s){
  return __uint_as_float(((unsigned)s) << 16);
}

// Wbf[j][k] = bf16(W[j][k]) : 1024 x 2048, rows >=784 zeroed
__global__ void conv_w(const float* __restrict__ W, unsigned short* __restrict__ Wbf){
  int i4 = (blockIdx.x*256 + threadIdx.x)*4;   // over 1024*2048 -> 2048 blocks
  int row = i4 >> 11;
  uint2 p = make_uint2(0,0);
  if (row < N_DIM){
    float4 v = *(const float4*)(W + (size_t)row*M_DIM + (i4 & 2047));
    p.x = pack2(v.x, v.y); p.y = pack2(v.z, v.w);
  }
  *(uint2*)(Wbf + i4) = p;
}

// Ybf[i][j] = bf16(Y[i][j]) : 8192 x 800, cols >=784 zeroed  (stored into Rbf buffer)
__global__ void conv_y(const float* __restrict__ Y, unsigned short* __restrict__ Ybf){
  int row = blockIdx.x;
  int c4 = threadIdx.x*4;
  if (c4 >= NPAD) return;
  uint2 p = make_uint2(0,0);
  if (c4 < N_DIM){
    float4 v = *(const float4*)(Y + (size_t)row*N_DIM + c4);
    p.x = pack2(v.x, v.y); p.y = pack2(v.z, v.w);
  }
  *(uint2*)(Ybf + (size_t)row*NPAD + c4) = p;
}

// WTbf[k][j] = bf16(W[j][k]) : 2048 x 800 (j in [784,800) -> 0)
__global__ void transpose_w(const float* __restrict__ W, unsigned short* __restrict__ WTbf){
  __shared__ float tile[32][33];
  int k0 = blockIdx.x*32;
  int j0 = blockIdx.y*32;
  int tx = threadIdx.x & 31, ty = threadIdx.x >> 5;
#pragma unroll
  for (int i=0;i<4;i++){
    int j = j0 + ty + 8*i;
    float v = (j < N_DIM) ? W[(size_t)j*M_DIM + k0 + tx] : 0.0f;
    tile[tx][ty+8*i] = v;
  }
  __syncthreads();
#pragma unroll
  for (int i=0;i<4;i++){
    int k = k0 + ty + 8*i;
    WTbf[(size_t)k*NPAD + j0 + tx] = f2bf(tile[ty+8*i][tx]);
  }
}

// ---------------- Qp = W W^T (784x784 fp32, one-time; power method runs in 784-space) ------
// Qp[a][b] = sum_k W[a,k]*W[b,k]. NT GEMM over K=2048, K contiguous -> coalesced loads.
__global__ __launch_bounds__(256)
void compute_qp(const float* __restrict__ W, float* __restrict__ Qp){
  __shared__ float As2[64][33];
  __shared__ float Bs2[64][33];
  const int t = threadIdx.x;
  const int a0 = blockIdx.x*64, b0 = blockIdx.y*64;
  const int ty = t>>4, tx = t&15;
  float acc[4][4];
#pragma unroll
  for (int i=0;i<4;i++)
#pragma unroll
    for (int j=0;j<4;j++) acc[i][j]=0.0f;

  for (int k0=0; k0<M_DIM; k0+=32){
#pragma unroll
    for (int h=0; h<2; ++h){
      int row = h*32 + (t>>3);
      int kq  = (t&7)*4;
      float4 av = make_float4(0,0,0,0), bv = make_float4(0,0,0,0);
      if (a0+row < N_DIM) av = *(const float4*)(W + (size_t)(a0+row)*M_DIM + k0 + kq);
      if (b0+row < N_DIM) bv = *(const float4*)(W + (size_t)(b0+row)*M_DIM + k0 + kq);
      As2[row][kq]=av.x; As2[row][kq+1]=av.y; As2[row][kq+2]=av.z; As2[row][kq+3]=av.w;
      Bs2[row][kq]=bv.x; Bs2[row][kq+1]=bv.y; Bs2[row][kq+2]=bv.z; Bs2[row][kq+3]=bv.w;
    }
    __syncthreads();
#pragma unroll
    for (int kk=0; kk<32; ++kk){
      float a[4], b[4];
#pragma unroll
      for (int i=0;i<4;i++) a[i] = As2[ty*4+i][kk];
#pragma unroll
      for (int j=0;j<4;j++) b[j] = Bs2[tx*4+j][kk];
#pragma unroll
      for (int i=0;i<4;i++)
#pragma unroll
        for (int j=0;j<4;j++) acc[i][j] = fmaf(a[i], b[j], acc[i][j]);
    }
    __syncthreads();
  }
#pragma unroll
  for (int i=0;i<4;i++){
    int a = a0 + ty*4 + i;
    if (a >= N_DIM) continue;
#pragma unroll
    for (int j=0;j<4;j++){
      int b = b0 + tx*4 + j;
      if (b < N_DIM) Qp[(size_t)a*N_DIM + b] = acc[i][j];
    }
  }
}

// u0[j] = sum_k x0[k]*W[j][k]  (u0 = X0 @ W^T, 784-vector)
__global__ void u0_kernel(const float* __restrict__ x0, const float* __restrict__ W,
                          float* __restrict__ u0){
  int wave = threadIdx.x>>6, lane = threadIdx.x&63;
  int j = blockIdx.x*4 + wave;           // grid 196 -> 784 rows
  const float* Wr = W + (size_t)j*M_DIM;
  float s = 0.0f;
  for (int k=lane; k<M_DIM; k+=64) s = fmaf(x0[k], Wr[k], s);
  for (int off=32; off>0; off>>=1) s += __shfl_down(s, off);
  if (lane==0) u0[j] = s;
}

// One power iteration in 784-space:
// u = vin / sqrt(din);  w[j] = (Qp u)[j];  dout += u[j]*w[j]  (=> dout = u Qp u^T = nm^2)
__global__ void pm_qp(const float* __restrict__ vin, const float* __restrict__ din,
                      const float* __restrict__ Qp,
                      float* __restrict__ vout, float* __restrict__ dout){
  int wave = threadIdx.x>>6, lane = threadIdx.x&63;
  int j = blockIdx.x*4 + wave;           // grid 196 -> 784 rows
  float inv = 1.0f/sqrtf(*din);
  const float* Qr = Qp + (size_t)j*N_DIM;
  float s = 0.0f;
  for (int k=lane; k<N_DIM; k+=64) s = fmaf(vin[k], Qr[k], s);
  for (int off=32; off>0; off>>=1) s += __shfl_down(s, off);
  if (lane==0){
    float w = s * inv;
    vout[j] = w;
    atomicAdd(dout, w * vin[j] * inv);
  }
}

// params: [0]=c, [1]=eta=1/c, [2]=lam/c, [3]=||Y||   (c = sqrt(d[100]) = nm_100)
__global__ void finish_power2(const float* __restrict__ d100, const float* __restrict__ accs,
                              float* __restrict__ params){
  float c = sqrtf(*d100);
  params[0] = c;
  params[1] = 1.0f/c;
  params[2] = 0.1f/c;
  params[3] = sqrtf(accs[0]);
}

// ---------------- reductions ----------------
__global__ void sumsq_kernel(const float* __restrict__ v, int n, float* __restrict__ acc){
  __shared__ float red[256];
  int t = threadIdx.x;
  float s = 0.0f;
  for (int i = blockIdx.x*256 + t; i < n; i += gridDim.x*256){ float x = v[i]; s = fmaf(x,x,s); }
  red[t] = s; __syncthreads();
  for (int off=128; off>0; off>>=1){ if (t<off) red[t]+=red[t+off]; __syncthreads(); }
  if (t==0) atomicAdd(acc, red[0]);
}

__device__ __forceinline__ float softthr(float v, float th){
  float a = fmaxf(fabsf(v) - th, 0.0f);
  return copysignf(a, v);
}

// ================= MFMA GEMM NT: C[i,j] = sum_k A[i,k]*B[j,k] =================
// Tile 64x256. Grid 512 (1D, XCD-swizzled: XCD g8 owns a 16m x 4n panel).
// Double-buffered K-loop; LDS bank-conflict fix: global source pre-swizzled so a quad's
// 16 lanes spread over 8 16B bank slots (2-way = free) on the ds_read_b128 fragment reads.
// A = Zhi bf16 [8192 x 2048], B = Wbf bf16 [1024 x 2048] (rows>=784 zero).
// MODE 0: R = A*B^T - Y -> Rbf (bf16, stride NPAD, cols [784,800) zeroed), ||R||^2 -> nacc.
// MODE 1: X = A*B^T (fp32 out; A holds bf16 of final Gamma).
template<int MODE>
__global__ __launch_bounds__(256)
void mfma_nt(const unsigned short* __restrict__ Abf,
             const unsigned short* __restrict__ Bbf,
             const float* __restrict__ Y,
             unsigned short* __restrict__ Rbf,
             float* __restrict__ X,
             float* __restrict__ nacc){
  __shared__ float4 smem4[2560];                 // 40 KB: (As 4KB + Bs 16KB) x2
  unsigned short* As0 = (unsigned short*)smem4;  // [64 x 32]
  unsigned short* Bs0 = As0 + 64*32;             // [256 x 32]
  unsigned short* As1 = Bs0 + 256*32;
  unsigned short* Bs1 = As1 + 64*32;
  float* fbuf = (float*)smem4;                   // [64 x 68] fp32 epilogue chunk (17.4 KB)

  const int bid = blockIdx.x;
  const int g8  = bid & 7, w = bid >> 3;         // XCD panel: 16m x 4n
  const int m0  = (g8*16 + (w>>2))*64;
  const int n0  = (w & 3)*256;

  const int t    = threadIdx.x;
  const int wave = t>>6, lane = t&63;
  const int wm2  = wave>>1, wn2 = wave&1;        // 2x2 waves over 64x256
  const int quad = lane>>4, l15 = lane&15;
  const int lrow = lane>>2;
  const int lks  = ((lane&3) ^ ((lrow>>1)&3))*8;           // swizzled k-quad for staging
  const int ksw  = (quad ^ ((l15>>1)&3))*8;                // swizzled k-quad for frag reads

  floatx4 acc[2][8];
#pragma unroll
  for (int i=0;i<2;i++)
#pragma unroll
    for (int j=0;j<8;j++) acc[i][j] = (floatx4)(0.0f);

  auto stage = [&](unsigned short* As, unsigned short* Bs, int k0){
    async_ld16(Abf + (size_t)(m0 + wave*16 + lrow)*M_DIM + k0 + lks, &As[wave*512]);
#pragma unroll
    for (int c=0; c<4; ++c){
      int chunk = wave*4 + c;
      async_ld16(Bbf + (size_t)(n0 + chunk*16 + lrow)*M_DIM + k0 + lks, &Bs[chunk*512]);
    }
  };

  stage(As0, Bs0, 0);
  __syncthreads();
  int cur = 0;
  for (int k0=0; k0<M_DIM; k0+=32, cur^=1){
    unsigned short* As = cur ? As1 : As0;
    unsigned short* Bs = cur ? Bs1 : Bs0;
    if (k0+32 < M_DIM) stage(cur ? As0 : As1, cur ? Bs0 : Bs1, k0+32);
    short8 af[2], bfr[8];
#pragma unroll
    for (int ti=0; ti<2; ++ti)
      af[ti] = *(const short8*)&As[(wm2*32 + ti*16 + l15)*32 + ksw];
#pragma unroll
    for (int tj=0; tj<8; ++tj)
      bfr[tj] = *(const short8*)&Bs[(wn2*128 + tj*16 + l15)*32 + ksw];
#pragma unroll
    for (int ti=0; ti<2; ++ti)
#pragma unroll
      for (int tj=0; tj<8; ++tj)
        acc[ti][tj] = __builtin_amdgcn_mfma_f32_16x16x32_bf16(af[ti], bfr[tj], acc[ti][tj], 0, 0, 0);
    __syncthreads();
  }

  // ---- coalesced epilogue: 4 chunks of [64 rows x 64 cols] via LDS (stride 68) ----
  float ss = 0.0f;
#pragma unroll
  for (int c=0; c<4; ++c){
    if (wn2 == (c>>1)){
      int tb = (c&1)*4;
#pragma unroll
      for (int ti=0; ti<2; ++ti)
#pragma unroll
        for (int u=0; u<4; ++u)
#pragma unroll
          for (int r=0; r<4; ++r)
            fbuf[(wm2*32 + ti*16 + quad*4 + r)*68 + u*16 + l15] = acc[ti][tb+u][r];
    }
    __syncthreads();
#pragma unroll
    for (int k=0; k<4; ++k){
      int row = k*16 + (t>>4);
      int col = (t&15)*4;
      int m = m0 + row;
      int n = n0 + c*64 + col;
      float4 v = *(const float4*)&fbuf[row*68 + col];
      if (MODE==0){
        if (n < N_DIM){
          float4 yv = *(const float4*)(Y + (size_t)m*N_DIM + n);
          float r0 = v.x - yv.x, r1 = v.y - yv.y, r2 = v.z - yv.z, r3 = v.w - yv.w;
          uint2 p; p.x = pack2(r0, r1); p.y = pack2(r2, r3);
          *(uint2*)(Rbf + (size_t)m*NPAD + n) = p;
          ss = fmaf(r0,r0, fmaf(r1,r1, fmaf(r2,r2, fmaf(r3,r3, ss))));
        } else if (n < NPAD){
          *(uint2*)(Rbf + (size_t)m*NPAD + n) = make_uint2(0,0);
        }
      } else {
        if (n < N_DIM) *(float4*)(X + (size_t)m*N_DIM + n) = v;
      }
    }
    __syncthreads();
  }

  if (MODE==0){
    for (int off=32; off>0; off>>=1) ss += __shfl_down(ss, off);
    if (lane==0) atomicAdd(nacc, ss);
  }
}

// ================= MFMA GEMM NN: G[i,n] = sum_j A[i,j]*WT[n,j] ==========
// Tile 128x128. Grid 1024 (XCD g8 owns an 8m x 16n panel). Double-buffered, swizzled LDS.
// State in MFMA-FRAGMENT layout (barrier-free epilogue, per-thread float4 coalesced):
//   Gf  fp32 frag [GSZ]  (aliased onto Gamma output region; MODE2 overwrites canonically)
//   Zf  fp32 frag [GSZ]  (full-precision Z; replaces hi/lo pair)
//   Zhi bf16 row-major   (written directly from fragments; A-operand of mfma_nt)
// Frag addr: ((blockL*16 + tile)*256 + t)*4 + r, tile = ti*4+tj, blockL = (m0>>7)*16+(n0>>7).
// MODE 0 (init, A=Ybf): g=soft(eta*G,0.1); Gf=g; Zf=g; Zhi=bf16(g).
// MODE 1 (iter, A=Rbf): g=soft(Zf-eta*G,lam/c); zn=g+mu*(g-Gf_old); Gf=g; Zf=zn; Zhi=bf16(zn).
// MODE 2 (last iter):   g=soft(Zf-eta*G,lam/c); canonical Gamma fp32 + Zhi via LDS roundtrip.
template<int MODE>
__global__ __launch_bounds__(256,3)
void mfma_nn(const unsigned short* __restrict__ Abf,
             const unsigned short* __restrict__ WTbf,
             float* __restrict__ Gamma,
             unsigned short* __restrict__ Zhi,
             float* __restrict__ Zf,
             float* __restrict__ Gf,
             const float* __restrict__ params,
             float mu){
  __shared__ float4 smem4[2048];                 // 32 KB: (As 8KB + Bs 8KB) x2
  unsigned short* As0 = (unsigned short*)smem4;  // [128 x 32]
  unsigned short* Bs0 = As0 + 128*32;            // [128 x 32]
  unsigned short* As1 = Bs0 + 128*32;
  unsigned short* Bs1 = As1 + 128*32;
  float* fbuf = (float*)smem4;                   // [128 x 36] fp32 epilogue chunk (MODE2)

  const int bid = blockIdx.x;
  const int g8  = bid & 7, w = bid >> 3;         // XCD panel: 8m x 16n
  const int m0  = (g8*8 + (w>>4))*128;
  const int n0  = (w & 15)*128;

  const int t    = threadIdx.x;
  const int wave = t>>6, lane = t&63;
  const int wm   = wave>>1, wn = wave&1;         // 2x2 waves over 128x128
  const int quad = lane>>4, l15 = lane&15;
  const int lrow = lane>>2;
  const int lks  = ((lane&3) ^ ((lrow>>1)&3))*8;
  const int ksw  = (quad ^ ((l15>>1)&3))*8;

  floatx4 acc[4][4];
#pragma unroll
  for (int i=0;i<4;i++)
#pragma unroll
    for (int j=0;j<4;j++) acc[i][j] = (floatx4)(0.0f);

  auto stage = [&](unsigned short* As, unsigned short* Bs, int k0){
#pragma unroll
    for (int c=0; c<2; ++c){
      int chunk = wave*2 + c;
      async_ld16(Abf  + (size_t)(m0 + chunk*16 + lrow)*NPAD + k0 + lks, &As[chunk*512]);
      async_ld16(WTbf + (size_t)(n0 + chunk*16 + lrow)*NPAD + k0 + lks, &Bs[chunk*512]);
    }
  };

  stage(As0, Bs0, 0);
  __syncthreads();
  int cur = 0;
  for (int k0=0; k0<NPAD; k0+=32, cur^=1){
    unsigned short* As = cur ? As1 : As0;
    unsigned short* Bs = cur ? Bs1 : Bs0;
    if (k0+32 < NPAD) stage(cur ? As0 : As1, cur ? Bs0 : Bs1, k0+32);
    short8 af[4], bfr[4];
#pragma unroll
    for (int ti=0; ti<4; ++ti)
      af[ti] = *(const short8*)&As[(wm*64 + ti*16 + l15)*32 + ksw];
#pragma unroll
    for (int tj=0; tj<4; ++tj)
      bfr[tj] = *(const short8*)&Bs[(wn*64 + tj*16 + l15)*32 + ksw];
#pragma unroll
    for (int ti=0; ti<4; ++ti)
#pragma unroll
      for (int tj=0; tj<4; ++tj)
        acc[ti][tj] = __builtin_amdgcn_mfma_f32_16x16x32_bf16(af[ti], bfr[tj], acc[ti][tj], 0, 0, 0);
    __syncthreads();
  }

  const float eta  = params[1];
  const float lamc = params[2];
  const size_t blockL = (size_t)((m0>>7)*16 + (n0>>7));
  float* GfB = Gf + blockL*16384 + (size_t)t*4;   // per-tile stride 1024 floats
  float* ZfB = Zf + blockL*16384 + (size_t)t*4;
  const int mrow0 = m0 + wm*64 + quad*4;          // row of reg r=0 for ti=0
  const int ncol  = n0 + wn*64 + l15;             // col for tj=0

  if (MODE==2){
    // transform acc in place (Zf frag read), then canonical roundtrip epilogue
#pragma unroll
    for (int ti=0; ti<4; ++ti)
#pragma unroll
      for (int tj=0; tj<4; ++tj){
        float4 zf4 = *(const float4*)(ZfB + (ti*4+tj)*1024);
        acc[ti][tj][0] = softthr(zf4.x - eta*acc[ti][tj][0], lamc);
        acc[ti][tj][1] = softthr(zf4.y - eta*acc[ti][tj][1], lamc);
        acc[ti][tj][2] = softthr(zf4.z - eta*acc[ti][tj][2], lamc);
        acc[ti][tj][3] = softthr(zf4.w - eta*acc[ti][tj][3], lamc);
      }
    __syncthreads();
#pragma unroll
    for (int c=0; c<4; ++c){
      if (wn == (c>>1)){
        int tb = (c&1)*2;
#pragma unroll
        for (int ti=0; ti<4; ++ti)
#pragma unroll
          for (int u=0; u<2; ++u)
#pragma unroll
            for (int r=0; r<4; ++r)
              fbuf[(wm*64 + ti*16 + quad*4 + r)*36 + u*16 + l15] = acc[ti][tb+u][r];
      }
      __syncthreads();
#pragma unroll
      for (int k=0; k<4; ++k){
        int row = k*32 + (t>>3);
        int col = (t&7)*4;
        int m = m0 + row;
        int n = n0 + c*32 + col;
        size_t idx = (size_t)m*M_DIM + n;
        float4 g4 = *(const float4*)&fbuf[row*36 + col];
        *(float4*)(Gamma + idx) = g4;
        uint2 phx; phx.x = pack2(g4.x, g4.y); phx.y = pack2(g4.z, g4.w);
        *(uint2*)(Zhi + idx) = phx;
      }
      __syncthreads();
    }
  } else {
    // barrier-free fragment epilogue
#pragma unroll
    for (int ti=0; ti<4; ++ti){
      float4 go4[4], zf4[4];
      if (MODE==1){
#pragma unroll
        for (int tj=0; tj<4; ++tj) go4[tj] = *(const float4*)(GfB + (ti*4+tj)*1024);
#pragma unroll
        for (int tj=0; tj<4; ++tj) zf4[tj] = *(const float4*)(ZfB + (ti*4+tj)*1024);
      }
#pragma unroll
      for (int tj=0; tj<4; ++tj){
        float gr[4], zn[4];
        if (MODE==1){
          float z[4]  = {zf4[tj].x, zf4[tj].y, zf4[tj].z, zf4[tj].w};
          float go[4] = {go4[tj].x, go4[tj].y, go4[tj].z, go4[tj].w};
#pragma unroll
          for (int r=0;r<4;r++){
            gr[r] = softthr(z[r] - eta*acc[ti][tj][r], lamc);
            zn[r] = gr[r] + mu*(gr[r] - go[r]);
          }
        } else {
#pragma unroll
          for (int r=0;r<4;r++){ gr[r] = softthr(eta*acc[ti][tj][r], 0.1f); zn[r] = gr[r]; }
        }
        *(float4*)(GfB + (ti*4+tj)*1024) = make_float4(gr[0],gr[1],gr[2],gr[3]);
        *(float4*)(ZfB + (ti*4+tj)*1024) = make_float4(zn[0],zn[1],zn[2],zn[3]);
        size_t zb = (size_t)(mrow0 + ti*16)*M_DIM + ncol + tj*16;
        Zhi[zb]            = f2bf(zn[0]);
        Zhi[zb + M_DIM]    = f2bf(zn[1]);
        Zhi[zb + 2*M_DIM]  = f2bf(zn[2]);
        Zhi[zb + 3*M_DIM]  = f2bf(zn[3]);
      }
    }
  }
}

__global__ void norms_finalize(const float* __restrict__ nacc, const float* __restrict__ params,
                               float* __restrict__ out){
  int i = threadIdx.x;
  if (i < NITER) out[i] = sqrtf(nacc[i]) / params[3];
}

extern "C" void kernel_launch(void* const* d_in, const int* in_sizes, int n_in,
                              void* d_out, int out_size, void* d_ws, size_t ws_size,
                              hipStream_t stream){
  const float* Y  = (const float*)d_in[0];
  const float* W  = (const float*)d_in[1];
  float* out      = (float*)d_out;
  float* X        = out;
  float* Gamma    = out + XSZ;
  float* norms    = out + XSZ + GSZ;

  // ---- scratch in ws (~124 MB; ws proven >= 134 MB) ----
  unsigned short* Zhi  = (unsigned short*)d_ws;            // [8192x2048] 33.55 MB (row-major)
  float* Zf            = (float*)(Zhi + (size_t)GSZ);      // [GSZ] fp32 frag 67.11 MB
  unsigned short* Rbf  = (unsigned short*)(Zf + (size_t)GSZ); // [8192x800] 13.11 MB (Ybf at init)
  unsigned short* Wbf  = Rbf  + (size_t)B_DIM*NPAD;        // [1024x2048]  4.19 MB
  unsigned short* WTbf = Wbf  + (size_t)NROWS_W*M_DIM;     // [2048x800]   3.28 MB
  float* Qp     = (float*)(WTbf + (size_t)M_DIM*NPAD);     // [784x784]    2.46 MB
  float* w0     = Qp + (size_t)N_DIM*N_DIM;                // 784-vec (1024 slot)
  float* w1     = w0 + 1024;
  float* dbuf   = w1 + 1024;     // d[0..100] power-method quadratic forms, d[0]=1
  float* params = dbuf + 128;
  float* accs   = params + 8;    // accs[0]=||Y||^2, accs[1..50]=per-iter ||R||^2
  float* xb0    = accs + 64;     // X0 threefry normals [2048]

  // Gf (fp32 fragment-layout Gamma state) aliases the Gamma output region;
  // MODE2 overwrites it canonically at the end.
  float* Gf = Gamma;

  setup_kernel<<<dim3(1), dim3(1024), 0, stream>>>(xb0, accs, dbuf);
  sumsq_kernel<<<dim3(512), dim3(256), 0, stream>>>(Y, XSZ, accs);
  conv_w      <<<dim3(2048), dim3(256), 0, stream>>>(W, Wbf);
  transpose_w <<<dim3(64,25), dim3(256), 0, stream>>>(W, WTbf);
  conv_y      <<<dim3(B_DIM), dim3(256), 0, stream>>>(Y, Rbf);   // Rbf := Ybf for init GEMM

  compute_qp<<<dim3(13,13), dim3(256), 0, stream>>>(W, Qp);
  u0_kernel <<<dim3(196), dim3(256), 0, stream>>>(xb0, W, w0);
  float* va = w0; float* vb = w1;
  for (int it=1; it<=PITER; ++it){
    pm_qp<<<dim3(196), dim3(256), 0, stream>>>(va, dbuf + it - 1, Qp, vb, dbuf + it);
    float* tmp = va; va = vb; vb = tmp;
  }
  finish_power2<<<dim3(1), dim3(1), 0, stream>>>(dbuf + PITER, accs, params);

  // Gamma0 = soft(eta*(Y@W), 0.1); Zf = Gamma0; Zhi = bf16(Gamma0)
  mfma_nn<0><<<dim3(1024), dim3(256), 0, stream>>>(Rbf, WTbf, Gamma, Zhi, Zf, Gf, params, 0.0f);

  float tcur = 1.0f;
  for (int it=0; it<NITER; ++it){
    mfma_nt<0><<<dim3(512), dim3(256), 0, stream>>>(Zhi, Wbf, Y, Rbf, nullptr, accs + 1 + it);
    float tsq = tcur*tcur;
    float tn  = (1.0f + sqrtf(1.0f + 4.0f*tsq)) / 2.0f;
    float mu  = (tcur - 1.0f) / tn;
    tcur = tn;
    if (it < NITER-1)
      mfma_nn<1><<<dim3(1024), dim3(256), 0, stream>>>(Rbf, WTbf, Gamma, Zhi, Zf, Gf, params, mu);
    else
      mfma_nn<2><<<dim3(1024), dim3(256), 0, stream>>>(Rbf, WTbf, Gamma, Zhi, Zf, Gf, params, mu);
  }

  norms_finalize<<<dim3(1), dim3(64), 0, stream>>>(accs + 1, params, norms);

  // X = Gamma @ W^T  (Zhi holds bf16 Gamma; Wbf in ws -> no aliasing, async B path)
  mfma_nt<1><<<dim3(512), dim3(256), 0, stream>>>(Zhi, Wbf, nullptr, nullptr, X, nullptr);
}